// Round 16
// baseline (192.712 us; speedup 1.0000x reference)
//
#include <hip/hip_runtime.h>
#include <stdint.h>

// GCN forward on MI355X.
// R14: FULL linear-tail collapse: logits = S·(S·(h0@P)) + (S·1)·q + bvec,
//   P = W1@(W2@Wc), q = b1@(W2@Wc). GEMM2 + conv1 (256-wide) deleted;
//   h0 never stored.
// R15: build_tail 1-block latency trap (~25-40us hidden) -> parallel matvec3.
// R16: gemm_u grid.y 2->1 (A-frag traffic 40->20MB), block owns all 256 cols,
//   epilogue: shfl-reduce -> LDS cross-wave sum -> direct t4a store.
//   Deletes 240K atomics, u buffer, u zeroing, build_t4a launch.
// R12: parallel 3-kernel scan (single-block scan was the same trap, 46.5us).
// R2 lesson: frag-major storage -> every GEMM load = 1KB coalesced burst.
// R13-R15: top-5 = harness 0xAA d_ws poison (~46us/fill, ~2/iter) — floor.

typedef __attribute__((ext_vector_type(8))) __bf16 bf16x8;
typedef __attribute__((ext_vector_type(4))) float f32x4;

static __device__ __forceinline__ unsigned short f32_to_bf16(float f) {
  uint32_t u = __float_as_uint(f);
  u += 0x7fffu + ((u >> 16) & 1u);   // RNE (finite data)
  return (unsigned short)(u >> 16);
}
static __device__ __forceinline__ float bf16_to_f32(unsigned short h) {
  return __uint_as_float(((uint32_t)h) << 16);
}
static __device__ __forceinline__ int frag_addr(int m, int k) {
  return (((m >> 4) * 8 + (k >> 5)) << 9) + (((m & 15) + 16 * ((k >> 3) & 3)) << 3) + (k & 7);
}

__global__ void zero_ints(int* __restrict__ p, int n) {
  int i = blockIdx.x * blockDim.x + threadIdx.x;
  if (i < n) p[i] = 0;
}

// edge_index may arrive as int32 or int64; detect on-device (values < 2^31,
// so an int64 array has every odd dword == 0 little-endian).
__global__ void detect_i64(const unsigned int* __restrict__ ei, int nwords,
                           int* __restrict__ flag) {
  __shared__ int any;
  if (threadIdx.x == 0) any = 0;
  __syncthreads();
  for (int i = 1 + 2 * (int)threadIdx.x; i < nwords; i += 2 * blockDim.x)
    if (ei[i] != 0u) any = 1;
  __syncthreads();
  if (threadIdx.x == 0) *flag = (any == 0) ? 1 : 0;
}

__global__ void count_deg(const int* __restrict__ ei, int E,
                          const int* __restrict__ flag, int* __restrict__ cnt) {
  int e = blockIdx.x * blockDim.x + threadIdx.x;
  int is64 = *flag;
  if (e < E) {
    int d = is64 ? ei[2 * (E + e)] : ei[E + e];
    atomicAdd(&cnt[d], 1);
  }
}

// --- parallel scan: block sums -> scan partials -> finalize ---
__global__ __launch_bounds__(256) void scan_partials(
    const int* __restrict__ cnt, int* __restrict__ partials, int n) {
  __shared__ int sdata[256];
  int i = blockIdx.x * 256 + threadIdx.x;
  sdata[threadIdx.x] = (i < n) ? cnt[i] : 0;
  __syncthreads();
  for (int off = 128; off > 0; off >>= 1) {
    if (threadIdx.x < off) sdata[threadIdx.x] += sdata[threadIdx.x + off];
    __syncthreads();
  }
  if (threadIdx.x == 0) partials[blockIdx.x] = sdata[0];
}

__global__ __launch_bounds__(1024) void scan_offsets(int* __restrict__ partials,
                                                     int nb) {
  __shared__ int sdata[1024];
  int tid = threadIdx.x;
  sdata[tid] = (tid < nb) ? partials[tid] : 0;
  __syncthreads();
  for (int off = 1; off < 1024; off <<= 1) {
    int t = (tid >= off) ? sdata[tid - off] : 0;
    __syncthreads();
    sdata[tid] += t;
    __syncthreads();
  }
  if (tid < nb) partials[tid] = sdata[tid];
}

__global__ __launch_bounds__(256) void scan_finalize(
    const int* __restrict__ cnt, const int* __restrict__ partials_inc,
    int* __restrict__ row_ptr, float* __restrict__ dinv, int n) {
  __shared__ int sdata[256];
  int b = blockIdx.x;
  int i = b * 256 + threadIdx.x;
  int v = (i < n) ? cnt[i] : 0;
  sdata[threadIdx.x] = v;
  __syncthreads();
  for (int off = 1; off < 256; off <<= 1) {
    int t = (threadIdx.x >= off) ? sdata[threadIdx.x - off] : 0;
    __syncthreads();
    sdata[threadIdx.x] += t;
    __syncthreads();
  }
  int incl = sdata[threadIdx.x];
  int base = (b > 0) ? partials_inc[b - 1] : 0;
  if (i < n) {
    row_ptr[i] = base + incl - v;                // exclusive prefix
    dinv[i] = 1.0f / sqrtf((float)(v + 1));      // +1 self-loop
    if (i == n - 1) row_ptr[n] = base + incl;    // total
  }
}

__global__ void fill_csr(const int* __restrict__ ei, int E,
                         const int* __restrict__ flag,
                         const int* __restrict__ row_ptr, int* __restrict__ cursor,
                         int* __restrict__ csr_src) {
  int e = blockIdx.x * blockDim.x + threadIdx.x;
  int is64 = *flag;
  if (e < E) {
    int s = is64 ? ei[2 * e] : ei[e];
    int d = is64 ? ei[2 * (E + e)] : ei[E + e];
    int pos = row_ptr[d] + atomicAdd(&cursor[d], 1);
    csr_src[pos] = s;
  }
}

// x f32 row-major -> A-fragment-major bf16 hi/lo.
__global__ void split_x_frag(const float4* __restrict__ in,
                             unsigned short* __restrict__ hi,
                             unsigned short* __restrict__ lo, int M) {
  int t = blockIdx.x * blockDim.x + threadIdx.x;
  if (t >= M * 32) return;
  int m = t >> 5, o = t & 31;              // o = k-octet
  float4 v0 = in[m * 64 + o * 2];
  float4 v1 = in[m * 64 + o * 2 + 1];
  float f[8] = {v0.x, v0.y, v0.z, v0.w, v1.x, v1.y, v1.z, v1.w};
  unsigned short hs[8], ls[8];
#pragma unroll
  for (int j = 0; j < 8; ++j) {
    unsigned short h = f32_to_bf16(f[j]);
    hs[j] = h;
    ls[j] = f32_to_bf16(f[j] - bf16_to_f32(h));
  }
  int addr = frag_addr(m, o * 8);
  *(ushort4*)(hi + addr) = make_ushort4(hs[0], hs[1], hs[2], hs[3]);
  *(ushort4*)(hi + addr + 4) = make_ushort4(hs[4], hs[5], hs[6], hs[7]);
  *(ushort4*)(lo + addr) = make_ushort4(ls[0], ls[1], ls[2], ls[3]);
  *(ushort4*)(lo + addr + 4) = make_ushort4(ls[4], ls[5], ls[6], ls[7]);
}

// W [k][n] row-major 256x256 -> B-fragment-major bf16 hi/lo.
__global__ void pack_w_frag(const float* __restrict__ W,
                            unsigned short* __restrict__ hi,
                            unsigned short* __restrict__ lo) {
  int k = blockIdx.x, n = threadIdx.x;
  float v = W[k * 256 + n];
  unsigned short h = f32_to_bf16(v);
  int addr = frag_addr(n, k);  // B-frag: same formula with n as row
  hi[addr] = h;
  lo[addr] = f32_to_bf16(v - bf16_to_f32(h));
}

// O3 = A @ B3   (A [256,256] row-major, B3 [256,3]); one wave per row k.
__global__ __launch_bounds__(256) void tail_matvec3(
    const float* __restrict__ A, const float* __restrict__ B3,
    float* __restrict__ O3) {
  int wid = threadIdx.x >> 6, lane = threadIdx.x & 63;
  int k = blockIdx.x * 4 + wid;
  float4 a = ((const float4*)(A + k * 256))[lane];
  int n0 = lane * 4;
  float s0 = a.x * B3[n0 * 3 + 0] + a.y * B3[n0 * 3 + 3] +
             a.z * B3[n0 * 3 + 6] + a.w * B3[n0 * 3 + 9];
  float s1 = a.x * B3[n0 * 3 + 1] + a.y * B3[n0 * 3 + 4] +
             a.z * B3[n0 * 3 + 7] + a.w * B3[n0 * 3 + 10];
  float s2 = a.x * B3[n0 * 3 + 2] + a.y * B3[n0 * 3 + 5] +
             a.z * B3[n0 * 3 + 8] + a.w * B3[n0 * 3 + 11];
#pragma unroll
  for (int off = 32; off > 0; off >>= 1) {
    s0 += __shfl_down(s0, off);
    s1 += __shfl_down(s1, off);
    s2 += __shfl_down(s2, off);
  }
  if (lane == 0) {
    O3[k * 3 + 0] = s0;
    O3[k * 3 + 1] = s1;
    O3[k * 3 + 2] = s2;
  }
}

// q = b1 @ w2wc;  bvec = b2 @ Wc + bc.  Two waves, one vector each.
__global__ __launch_bounds__(128) void tail_vec(
    const float* __restrict__ b1, const float* __restrict__ w2wc,
    const float* __restrict__ b2, const float* __restrict__ Wc,
    const float* __restrict__ bc, float* __restrict__ q,
    float* __restrict__ bvec) {
  int wid = threadIdx.x >> 6, lane = threadIdx.x & 63;
  const float* vin = (wid == 0) ? b1 : b2;
  const float* mat = (wid == 0) ? w2wc : Wc;
  float4 a = ((const float4*)vin)[lane];
  int n0 = lane * 4;
  float s0 = a.x * mat[n0 * 3 + 0] + a.y * mat[n0 * 3 + 3] +
             a.z * mat[n0 * 3 + 6] + a.w * mat[n0 * 3 + 9];
  float s1 = a.x * mat[n0 * 3 + 1] + a.y * mat[n0 * 3 + 4] +
             a.z * mat[n0 * 3 + 7] + a.w * mat[n0 * 3 + 10];
  float s2 = a.x * mat[n0 * 3 + 2] + a.y * mat[n0 * 3 + 5] +
             a.z * mat[n0 * 3 + 8] + a.w * mat[n0 * 3 + 11];
#pragma unroll
  for (int off = 32; off > 0; off >>= 1) {
    s0 += __shfl_down(s0, off);
    s1 += __shfl_down(s1, off);
    s2 += __shfl_down(s2, off);
  }
  if (lane == 0) {
    if (wid == 0) {
      q[0] = s0; q[1] = s1; q[2] = s2;
    } else {
      bvec[0] = s0 + bc[0]; bvec[1] = s1 + bc[1]; bvec[2] = s2 + bc[2];
    }
  }
}

// GEMM1 + fused u-reduction + t4a build (R16).
// One block = 64 rows x ALL 256 cols; 4 waves (wm in {0,1} x wn in {0,1});
// wave = 2 mtiles x 8 ntiles, acc[2][8]. A-frags read ONCE (20MB total).
// Epilogue: per-thread 3-dot with P over its 8 cols -> shfl-reduce over the
// 16 r-lanes -> LDS cross-wn sum -> 64 threads store t4a=(d*u, d) directly.
// No atomics, no u buffer.
__global__ __launch_bounds__(256) void gemm_u(
    const unsigned short* __restrict__ Ahi, const unsigned short* __restrict__ Alo,
    const unsigned short* __restrict__ Bhi, const unsigned short* __restrict__ Blo,
    int M, const float* __restrict__ bias, const float* __restrict__ P,
    const float* __restrict__ dinv, float4* __restrict__ t4a) {
  __shared__ float lds_u[2][64][3];
  int wid = threadIdx.x >> 6, lane = threadIdx.x & 63;
  int wm = wid & 1, wn = wid >> 1;
  int Mtiles = (M + 15) >> 4;
  int mt_base = blockIdx.x * 4 + wm * 2;
  int la8 = lane * 8;

  int mt0 = mt_base < Mtiles ? mt_base : Mtiles - 1;
  int mt1 = mt_base + 1 < Mtiles ? mt_base + 1 : Mtiles - 1;
  const unsigned short* a0h = Ahi + mt0 * 4096 + la8;
  const unsigned short* a0l = Alo + mt0 * 4096 + la8;
  const unsigned short* a1h = Ahi + mt1 * 4096 + la8;
  const unsigned short* a1l = Alo + mt1 * 4096 + la8;
  const unsigned short* bh = Bhi + wn * 8 * 4096 + la8;
  const unsigned short* bl = Blo + wn * 8 * 4096 + la8;

  f32x4 acc[2][8] = {};
#pragma unroll
  for (int k0 = 0; k0 < 8; ++k0) {
    bf16x8 A0h = *(const bf16x8*)(a0h + k0 * 512);
    bf16x8 A0l = *(const bf16x8*)(a0l + k0 * 512);
    bf16x8 A1h = *(const bf16x8*)(a1h + k0 * 512);
    bf16x8 A1l = *(const bf16x8*)(a1l + k0 * 512);
#pragma unroll
    for (int ni = 0; ni < 8; ++ni) {
      bf16x8 Bh = *(const bf16x8*)(bh + ni * 4096 + k0 * 512);
      bf16x8 Bl = *(const bf16x8*)(bl + ni * 4096 + k0 * 512);
      acc[0][ni] = __builtin_amdgcn_mfma_f32_16x16x32_bf16(A0h, Bh, acc[0][ni], 0, 0, 0);
      acc[0][ni] = __builtin_amdgcn_mfma_f32_16x16x32_bf16(A0h, Bl, acc[0][ni], 0, 0, 0);
      acc[0][ni] = __builtin_amdgcn_mfma_f32_16x16x32_bf16(A0l, Bh, acc[0][ni], 0, 0, 0);
      acc[1][ni] = __builtin_amdgcn_mfma_f32_16x16x32_bf16(A1h, Bh, acc[1][ni], 0, 0, 0);
      acc[1][ni] = __builtin_amdgcn_mfma_f32_16x16x32_bf16(A1h, Bl, acc[1][ni], 0, 0, 0);
      acc[1][ni] = __builtin_amdgcn_mfma_f32_16x16x32_bf16(A1l, Bh, acc[1][ni], 0, 0, 0);
    }
  }

  int r = lane & 15, g = lane >> 4;
  float rp[8][3];
#pragma unroll
  for (int t = 0; t < 8; ++t) { rp[t][0] = 0.f; rp[t][1] = 0.f; rp[t][2] = 0.f; }
#pragma unroll
  for (int mi = 0; mi < 2; ++mi) {
#pragma unroll
    for (int ii = 0; ii < 4; ++ii) {
      int ri = mi * 4 + ii;
#pragma unroll
      for (int ni = 0; ni < 8; ++ni) {
        int col = (wn * 8 + ni) * 16 + r;
        float v = fmaxf(acc[mi][ni][ii] + bias[col], 0.0f);
        rp[ri][0] += v * P[col * 3 + 0];
        rp[ri][1] += v * P[col * 3 + 1];
        rp[ri][2] += v * P[col * 3 + 2];
      }
    }
  }
  // reduce over the 16 r-lanes (rows shared across r, cols differ)
#pragma unroll
  for (int t = 0; t < 8; ++t) {
#pragma unroll
    for (int c = 0; c < 3; ++c) {
      float v = rp[t][c];
      v += __shfl_down(v, 8, 16);
      v += __shfl_down(v, 4, 16);
      v += __shfl_down(v, 2, 16);
      v += __shfl_down(v, 1, 16);
      rp[t][c] = v;
    }
  }
  if (r == 0) {
#pragma unroll
    for (int mi = 0; mi < 2; ++mi) {
#pragma unroll
      for (int ii = 0; ii < 4; ++ii) {
        int lrow = wm * 32 + mi * 16 + g * 4 + ii;
        int ri = mi * 4 + ii;
        lds_u[wn][lrow][0] = rp[ri][0];
        lds_u[wn][lrow][1] = rp[ri][1];
        lds_u[wn][lrow][2] = rp[ri][2];
      }
    }
  }
  __syncthreads();
  int t = threadIdx.x;
  if (t < 64) {
    int grow = blockIdx.x * 64 + t;
    if (grow < M) {
      float d = dinv[grow];
      float u0 = lds_u[0][t][0] + lds_u[1][t][0];
      float u1 = lds_u[0][t][1] + lds_u[1][t][1];
      float u2 = lds_u[0][t][2] + lds_u[1][t][2];
      t4a[grow] = make_float4(d * u0, d * u1, d * u2, d);
    }
  }
}

// passA: s = sum t4a[src] + t4a[i];  t4b[i] = (dinv_i^2*s.xyz, dinv_i*s.w).
__global__ void conv_skinnyA(const float4* __restrict__ t4a,
                             const int* __restrict__ row_ptr,
                             const int* __restrict__ csr_src,
                             const float* __restrict__ dinv,
                             float4* __restrict__ t4b, int n) {
  int i = blockIdx.x * blockDim.x + threadIdx.x;
  if (i >= n) return;
  int e = row_ptr[i], e1 = row_ptr[i + 1];
  float a0 = 0.f, a1 = 0.f, a2 = 0.f, a3 = 0.f;
  float b0 = 0.f, b1 = 0.f, b2 = 0.f, b3 = 0.f;
  for (; e + 1 < e1; e += 2) {
    float4 v0 = t4a[csr_src[e]];
    float4 v1 = t4a[csr_src[e + 1]];
    a0 += v0.x; a1 += v0.y; a2 += v0.z; a3 += v0.w;
    b0 += v1.x; b1 += v1.y; b2 += v1.z; b3 += v1.w;
  }
  if (e < e1) {
    float4 v0 = t4a[csr_src[e]];
    a0 += v0.x; a1 += v0.y; a2 += v0.z; a3 += v0.w;
  }
  float4 self = t4a[i];
  float d = dinv[i];
  float d2 = d * d;
  t4b[i] = make_float4(d2 * (a0 + b0 + self.x), d2 * (a1 + b1 + self.y),
                       d2 * (a2 + b2 + self.z), d * (a3 + b3 + self.w));
}

// passB: logits_i = dinv_i*(sum t4b[src].xyz + t4b[i].xyz) + q*r_i + bvec.
__global__ void conv_skinnyB(const float4* __restrict__ t4b,
                             const int* __restrict__ row_ptr,
                             const int* __restrict__ csr_src,
                             const float* __restrict__ dinv,
                             const float* __restrict__ q,
                             const float* __restrict__ bvec,
                             float* __restrict__ out, int n) {
  int i = blockIdx.x * blockDim.x + threadIdx.x;
  if (i >= n) return;
  int e = row_ptr[i], e1 = row_ptr[i + 1];
  float a0 = 0.f, a1 = 0.f, a2 = 0.f;
  float b0 = 0.f, b1 = 0.f, b2 = 0.f;
  for (; e + 1 < e1; e += 2) {
    float4 v0 = t4b[csr_src[e]];
    float4 v1 = t4b[csr_src[e + 1]];
    a0 += v0.x; a1 += v0.y; a2 += v0.z;
    b0 += v1.x; b1 += v1.y; b2 += v1.z;
  }
  if (e < e1) {
    float4 v0 = t4b[csr_src[e]];
    a0 += v0.x; a1 += v0.y; a2 += v0.z;
  }
  float4 self = t4b[i];
  float d = dinv[i];
  float r = self.w;
  out[i * 3 + 0] = d * (a0 + b0 + self.x) + q[0] * r + bvec[0];
  out[i * 3 + 1] = d * (a1 + b1 + self.y) + q[1] * r + bvec[1];
  out[i * 3 + 2] = d * (a2 + b2 + self.z) + q[2] * r + bvec[2];
}

extern "C" void kernel_launch(void* const* d_in, const int* in_sizes, int n_in,
                              void* d_out, int out_size, void* d_ws, size_t ws_size,
                              hipStream_t stream) {
  const float* x = (const float*)d_in[0];
  const int* ei = (const int*)d_in[1];
  const float* W_embed = (const float*)d_in[2];
  const float* b_embed = (const float*)d_in[3];
  const float* W1 = (const float*)d_in[4];
  const float* b1 = (const float*)d_in[5];
  const float* W2 = (const float*)d_in[6];
  const float* b2 = (const float*)d_in[7];
  const float* Wcls = (const float*)d_in[8];
  const float* bcls = (const float*)d_in[9];
  const int N = in_sizes[0] / 256;   // 20000
  const int E = in_sizes[1] / 2;     // 320000

  char* ws = (char*)d_ws;
  size_t off = 0;
  auto alloc = [&](size_t bytes) {
    void* p = ws + off;
    off = (off + bytes + 255) & ~(size_t)255;
    return p;
  };
  int* cnt = (int*)alloc((size_t)N * 4);
  int* cursor = (int*)alloc((size_t)N * 4);
  int* row_ptr = (int*)alloc((size_t)(N + 1) * 4);
  float* dinv = (float*)alloc((size_t)N * 4);
  int* csr_src = (int*)alloc((size_t)E * 4);
  int* flag = (int*)alloc(256);
  int* partials = (int*)alloc(4096);
  unsigned short* WemFhi = (unsigned short*)alloc(256 * 256 * 2);
  unsigned short* WemFlo = (unsigned short*)alloc(256 * 256 * 2);
  float* w2wc = (float*)alloc(256 * 3 * 4);
  float* P = (float*)alloc(256 * 3 * 4);
  float* q = (float*)alloc(256);
  float* bvec = (float*)alloc(256);
  float4* t4a = (float4*)alloc((size_t)N * 16);
  float4* t4b = (float4*)alloc((size_t)N * 16);
  size_t big = (size_t)N * 256;
  unsigned short* P1hi = (unsigned short*)alloc(big * 4);  // x frags (hi|lo)
  unsigned short* P1lo = P1hi + big;

  int nb = (N + 255) / 256;  // scan chunks
  int nz = (int)(((char*)row_ptr - (char*)cnt) / 4);  // cnt + cursor (incl pad)
  zero_ints<<<(nz + 255) / 256, 256, 0, stream>>>(cnt, nz);
  detect_i64<<<1, 256, 0, stream>>>((const unsigned int*)ei, 4096, flag);
  count_deg<<<(E + 255) / 256, 256, 0, stream>>>(ei, E, flag, cnt);
  scan_partials<<<nb, 256, 0, stream>>>(cnt, partials, N);
  scan_offsets<<<1, 1024, 0, stream>>>(partials, nb);
  scan_finalize<<<nb, 256, 0, stream>>>(cnt, partials, row_ptr, dinv, N);
  fill_csr<<<(E + 255) / 256, 256, 0, stream>>>(ei, E, flag, row_ptr, cursor, csr_src);

  split_x_frag<<<(N * 32 + 255) / 256, 256, 0, stream>>>((const float4*)x, P1hi, P1lo, N);
  pack_w_frag<<<256, 256, 0, stream>>>(W_embed, WemFhi, WemFlo);
  // tail weights: w2wc = W2@Wc;  P = W1@w2wc;  q = b1@w2wc;  bvec = b2@Wc + bc
  tail_matvec3<<<64, 256, 0, stream>>>(W2, Wcls, w2wc);
  tail_matvec3<<<64, 256, 0, stream>>>(W1, w2wc, P);
  tail_vec<<<1, 128, 0, stream>>>(b1, w2wc, b2, Wcls, bcls, q, bvec);

  // u = relu(x@We + be) @ P fused into t4a = (dinv*u, dinv); no atomics
  gemm_u<<<(N + 63) / 64, 256, 0, stream>>>(P1hi, P1lo, WemFhi, WemFlo, N,
                                            b_embed, P, dinv, t4a);
  // passA: t4b = (dinv*(S.(h0@P)), S.1)
  conv_skinnyA<<<(N + 255) / 256, 256, 0, stream>>>(t4a, row_ptr, csr_src, dinv,
                                                    t4b, N);
  // passB: logits
  conv_skinnyB<<<(N + 255) / 256, 256, 0, stream>>>(t4b, row_ptr, csr_src, dinv,
                                                    q, bvec, (float*)d_out, N);
}